// Round 10
// baseline (103940.747 us; speedup 1.0000x reference)
//
#include <hip/hip_runtime.h>
#include <math.h>

#define T_STEPS 65536
#define HID     512
#define NWG     64
#define WGSIZE  256

// R2/R9 sync primitive (proven fastest) + single barrier/step + 2-deep x prefetch.
//
// Layout per workgroup (256 thr = 4 waves):
//   WG owns 8 h-indices: [wg*8, wg*8+8).
//   Wave wid owns 2 h-indices: wg*8 + wid*2 + {0,1}.
//   lane = r + 8*g: r -> (jloc=r&1, gate=r>>1) (PyTorch i,f,g,o), g = k-group.
//   Each lane holds 64 fp32 of W_hh and 64 of W_ih (asm-pinned).
//
// Step structure (ONE barrier):
//   staging:  poll h_{t-1} -> hl[t&1];  write xv(=x_{t+1}) -> xl[(t+1)&1]
//   B1
//   compute:  issue load x_{t+2} -> xv   (drains under compute+next poll)
//             acc = xacc + dot(hl[t&1]); gates; post h_t (tagged, agent atomic)
//             xacc = dot(xl[(t+1)&1])    (for t+1; also hides post landing)
//
// Buffer safety with one barrier: reader of hl[t&1] is in compute(t)
// (pre-B1(t+1)); next writer is staging(t+2) (post-B1(t+1)). Reader of
// xl[t&1] is compute(t-1) (pre-B1(t)); next writer staging(t+1) (post-B1(t)).

__global__ __launch_bounds__(WGSIZE, 1)
void lstm_persistent(const float* __restrict__ x,      // [T,512]
                     const float* __restrict__ Wih,    // [2048,512]
                     const float* __restrict__ Whh,    // [2048,512]
                     const float* __restrict__ bih,    // [2048]
                     const float* __restrict__ bhh,    // [2048]
                     float* __restrict__ out,          // [512]
                     unsigned long long* hbuf)         // [2][512] tagged pairs
{
  const int wg   = blockIdx.x;
  const int tid  = threadIdx.x;
  const int wid  = tid >> 6;
  const int lane = tid & 63;
  const int r    = lane & 7;
  const int g    = lane >> 3;
  const int k0   = g << 6;            // 64-float k-slice start
  const int jloc = r & 1;
  const int gate = r >> 1;            // 0=i 1=f 2=g 3=o
  const int hidx = wg * 8 + wid * 2 + jloc;
  const int row  = gate * HID + hidx;

  __shared__ __align__(16) float hl[2][512];
  __shared__ __align__(16) float xl[2][512];

  // ---- load weights into registers (static indices only) ----
  float whh[64], wih[64];
#pragma unroll
  for (int i = 0; i < 16; ++i) {
    const int kk = k0 + (((i + g) & 15) << 2);
    float4 a = *reinterpret_cast<const float4*>(Whh + (size_t)row * 512 + kk);
    float4 b = *reinterpret_cast<const float4*>(Wih + (size_t)row * 512 + kk);
    whh[4*i+0] = a.x; whh[4*i+1] = a.y; whh[4*i+2] = a.z; whh[4*i+3] = a.w;
    wih[4*i+0] = b.x; wih[4*i+1] = b.y; wih[4*i+2] = b.z; wih[4*i+3] = b.w;
  }
  float bias = bih[row] + bhh[row];

  // ---- pin: values opaque -> no in-loop rematerialization ----
#pragma unroll
  for (int i = 0; i < 64; ++i) {
    asm volatile("" : "+v"(whh[i]));
    asm volatile("" : "+v"(wih[i]));
  }
  asm volatile("" : "+v"(bias));

  // ---- stage x_0; prefetch x_1 into registers ----
  if (tid < 128) {
    float4 v = reinterpret_cast<const float4*>(x)[tid];
    *reinterpret_cast<float4*>(&xl[0][tid * 4]) = v;
  }
  float4 xv;
  if (tid < 128) xv = reinterpret_cast<const float4*>(x + (size_t)512)[tid];
  __syncthreads();

  auto dot_lds = [&](const float* lds, const float* w) -> float {
    float acc = 0.f;
#pragma unroll
    for (int i = 0; i < 16; ++i) {
      const int kk = k0 + (((i + g) & 15) << 2);
      float4 v = *reinterpret_cast<const float4*>(lds + kk);
      acc = fmaf(w[4*i+0], v.x, acc);
      acc = fmaf(w[4*i+1], v.y, acc);
      acc = fmaf(w[4*i+2], v.z, acc);
      acc = fmaf(w[4*i+3], v.w, acc);
    }
    return acc;
  };

  float xacc = dot_lds(xl[0], wih);   // x-projection partial for t=0
  float c    = 0.f;

#pragma unroll 1
  for (int t = 0; t < T_STEPS; ++t) {
    // ======== staging region ========
    // poll h_{t-1} FIRST (its vmcnt(0) also drains last step's x load)
    if (t > 0) {
      const unsigned long long* src = hbuf + (((t - 1) & 1) << 9) + (tid << 1);
      const unsigned exp = (unsigned)t;
      unsigned long long p0, p1;
      while (true) {
        p0 = __hip_atomic_load(src + 0, __ATOMIC_RELAXED, __HIP_MEMORY_SCOPE_AGENT);
        p1 = __hip_atomic_load(src + 1, __ATOMIC_RELAXED, __HIP_MEMORY_SCOPE_AGENT);
        if ((unsigned)(p0 >> 32) == exp && (unsigned)(p1 >> 32) == exp) break;
      }
      hl[t & 1][(tid << 1) + 0] = __uint_as_float((unsigned)p0);
      hl[t & 1][(tid << 1) + 1] = __uint_as_float((unsigned)p1);
    }
    if ((tid < 128) && (t + 1 < T_STEPS))
      *reinterpret_cast<float4*>(&xl[(t + 1) & 1][tid * 4]) = xv;   // xv = x_{t+1}
    __syncthreads();   // single barrier per step

    // ======== compute region ========
    // issue x_{t+2} now: ~500ns of compute + next poll drain its latency
    if ((tid < 128) && (t + 2 < T_STEPS))
      xv = reinterpret_cast<const float4*>(x + (size_t)(t + 2) * 512)[tid];

    float acc = xacc;
    if (t > 0) acc += dot_lds(hl[t & 1], whh);
    acc += __shfl_xor(acc, 8);
    acc += __shfl_xor(acc, 16);
    acc += __shfl_xor(acc, 32);
    acc += bias;

    // sigmoid for i,f,o; tanh (=2*sig(2x)-1) for g
    const bool isg = (gate == 2);
    float xs = isg ? 2.f * acc : acc;
    float s  = 1.f / (1.f + expf(-xs));
    float v  = isg ? (2.f * s - 1.f) : s;

    // gather i,f,g,o for my jloc via in-wave shuffles
    float iv = __shfl(v, jloc + 0);
    float fv = __shfl(v, jloc + 2);
    float gv = __shfl(v, jloc + 4);
    float ov = __shfl(v, jloc + 6);

    c = fv * c + iv * gv;
    float e2 = expf(-2.f * c);
    float th = 2.f / (1.f + e2) - 1.f;
    float hn = ov * th;

    // post tagged h_t (lanes 0,1 of every wave): fire-and-forget agent atomic
    if (lane < 2) {
      unsigned long long pk =
          ((unsigned long long)(unsigned)(t + 1) << 32) | (unsigned)__float_as_uint(hn);
      __hip_atomic_store(hbuf + ((t & 1) << 9) + wg * 8 + wid * 2 + lane, pk,
                         __ATOMIC_RELAXED, __HIP_MEMORY_SCOPE_AGENT);
    }

    // x-projection partial for t+1 (reads xl[(t+1)&1]; hides post landing)
    if (t + 1 < T_STEPS) xacc = dot_lds(xl[(t + 1) & 1], wih);
  }

  // ---- softmax(h_{T-1}) by wg 0, wave 0 ----
  if (wg == 0 && wid == 0) {
    const unsigned long long* src = hbuf + (((T_STEPS - 1) & 1) << 9);
    float hv[8];
    {
      unsigned long long p[8];
      while (true) {
        bool ok = true;
#pragma unroll
        for (int m2 = 0; m2 < 8; ++m2) {
          p[m2] = __hip_atomic_load(src + lane * 8 + m2,
                                    __ATOMIC_RELAXED, __HIP_MEMORY_SCOPE_AGENT);
          ok &= ((unsigned)(p[m2] >> 32) == (unsigned)T_STEPS);
        }
        if (__all(ok)) break;
      }
#pragma unroll
      for (int m2 = 0; m2 < 8; ++m2) hv[m2] = __uint_as_float((unsigned)p[m2]);
    }
    float mx = hv[0];
#pragma unroll
    for (int m2 = 1; m2 < 8; ++m2) mx = fmaxf(mx, hv[m2]);
    mx = fmaxf(mx, __shfl_xor(mx, 1));
    mx = fmaxf(mx, __shfl_xor(mx, 2));
    mx = fmaxf(mx, __shfl_xor(mx, 4));
    mx = fmaxf(mx, __shfl_xor(mx, 8));
    mx = fmaxf(mx, __shfl_xor(mx, 16));
    mx = fmaxf(mx, __shfl_xor(mx, 32));
    float ex[8], sum = 0.f;
#pragma unroll
    for (int m2 = 0; m2 < 8; ++m2) { ex[m2] = expf(hv[m2] - mx); sum += ex[m2]; }
    sum += __shfl_xor(sum, 1);
    sum += __shfl_xor(sum, 2);
    sum += __shfl_xor(sum, 4);
    sum += __shfl_xor(sum, 8);
    sum += __shfl_xor(sum, 16);
    sum += __shfl_xor(sum, 32);
    float inv = 1.f / sum;
#pragma unroll
    for (int m2 = 0; m2 < 8; ++m2) out[lane * 8 + m2] = ex[m2] * inv;
  }
}

extern "C" void kernel_launch(void* const* d_in, const int* in_sizes, int n_in,
                              void* d_out, int out_size, void* d_ws, size_t ws_size,
                              hipStream_t stream) {
  const float* x   = (const float*)d_in[0];
  const float* Wih = (const float*)d_in[1];
  const float* Whh = (const float*)d_in[2];
  const float* bih = (const float*)d_in[3];
  const float* bhh = (const float*)d_in[4];
  float* out = (float*)d_out;
  unsigned long long* hbuf = (unsigned long long*)d_ws;  // 2 x 512 x 8B = 8 KB

  (void)hipMemsetAsync(d_ws, 0, 8192, stream);  // zero tags each launch (capture-safe)
  lstm_persistent<<<NWG, WGSIZE, 0, stream>>>(x, Wih, Whh, bih, bhh, out, hbuf);
}

// Round 11
// 99316.492 us; speedup vs baseline: 1.0466x; 1.0466x over previous
//
#include <hip/hip_runtime.h>
#include <math.h>

#define T_STEPS 65536
#define HID     512
#define NWG     64
#define WGSIZE  256

typedef float f2v __attribute__((ext_vector_type(2)));

// R10 skeleton (proven: agent-atomic tagged mailbox, 1 barrier/step, 2-deep x
// register prefetch) + R11 critical-path compute shave:
//   - dot_lds: 4 accumulators (FMA dep chain 64 -> 16)
//   - gates: exp2f (v_exp_f32) + v_rcp_f32 instead of expf + exact div
//   - gate gather: static ds_swizzle (not ds_bpermute __shfl)
//   - reduce over k-groups: swizzle-xor for 8/16, __shfl_xor for 32
//
// Layout per workgroup (256 thr = 4 waves):
//   WG owns 8 h-indices: [wg*8, wg*8+8).
//   lane = r + 8*g: r -> (jloc=r&1, gate=r>>1) (PyTorch i,f,g,o), g = k-group.
//   Each lane holds 64 fp32 of W_hh and 64 of W_ih (asm-pinned).

__global__ __launch_bounds__(WGSIZE, 1)
void lstm_persistent(const float* __restrict__ x,      // [T,512]
                     const float* __restrict__ Wih,    // [2048,512]
                     const float* __restrict__ Whh,    // [2048,512]
                     const float* __restrict__ bih,    // [2048]
                     const float* __restrict__ bhh,    // [2048]
                     float* __restrict__ out,          // [512]
                     unsigned long long* hbuf)         // [2][512] tagged pairs
{
  const int wg   = blockIdx.x;
  const int tid  = threadIdx.x;
  const int wid  = tid >> 6;
  const int lane = tid & 63;
  const int r    = lane & 7;
  const int g    = lane >> 3;
  const int k0   = g << 6;            // 64-float k-slice start
  const int jloc = r & 1;
  const int gate = r >> 1;            // 0=i 1=f 2=g 3=o
  const int hidx = wg * 8 + wid * 2 + jloc;
  const int row  = gate * HID + hidx;

  __shared__ __align__(16) float hl[2][512];
  __shared__ __align__(16) float xl[2][512];

  // ---- load weights into registers (static indices only) ----
  float whh[64], wih[64];
#pragma unroll
  for (int i = 0; i < 16; ++i) {
    const int kk = k0 + (((i + g) & 15) << 2);
    float4 a = *reinterpret_cast<const float4*>(Whh + (size_t)row * 512 + kk);
    float4 b = *reinterpret_cast<const float4*>(Wih + (size_t)row * 512 + kk);
    whh[4*i+0] = a.x; whh[4*i+1] = a.y; whh[4*i+2] = a.z; whh[4*i+3] = a.w;
    wih[4*i+0] = b.x; wih[4*i+1] = b.y; wih[4*i+2] = b.z; wih[4*i+3] = b.w;
  }
  float bias = bih[row] + bhh[row];

  // ---- pin weight values (no in-loop rematerialization) ----
#pragma unroll
  for (int i = 0; i < 64; ++i) {
    asm volatile("" : "+v"(whh[i]));
    asm volatile("" : "+v"(wih[i]));
  }
  asm volatile("" : "+v"(bias));

  // ---- stage x_0; prefetch x_1 into registers ----
  if (tid < 128) {
    float4 v = reinterpret_cast<const float4*>(x)[tid];
    *reinterpret_cast<float4*>(&xl[0][tid * 4]) = v;
  }
  float4 xv;
  if (tid < 128) xv = reinterpret_cast<const float4*>(x + (size_t)512)[tid];
  __syncthreads();

  // 4 rotating accumulators: FMA dep chain 16 instead of 64.
  auto dot_lds = [&](const float* lds, const float* w) -> float {
    float a0 = 0.f, a1 = 0.f, a2 = 0.f, a3 = 0.f;
#pragma unroll
    for (int i = 0; i < 16; ++i) {
      const int kk = k0 + (((i + g) & 15) << 2);
      float4 v = *reinterpret_cast<const float4*>(lds + kk);
      a0 = fmaf(w[4*i+0], v.x, a0);
      a1 = fmaf(w[4*i+1], v.y, a1);
      a2 = fmaf(w[4*i+2], v.z, a2);
      a3 = fmaf(w[4*i+3], v.w, a3);
    }
    return (a0 + a1) + (a2 + a3);
  };

  const float LOG2E  = 1.4426950408889634f;
  const float LOG2E2 = 2.8853900817779268f;

  float xacc = dot_lds(xl[0], wih);   // x-projection partial for t=0
  float c    = 0.f;

#pragma unroll 1
  for (int t = 0; t < T_STEPS; ++t) {
    // ======== staging region ========
    if (t > 0) {
      const unsigned long long* src = hbuf + (((t - 1) & 1) << 9) + (tid << 1);
      const unsigned exp = (unsigned)t;
      unsigned long long p0, p1;
      while (true) {
        p0 = __hip_atomic_load(src + 0, __ATOMIC_RELAXED, __HIP_MEMORY_SCOPE_AGENT);
        p1 = __hip_atomic_load(src + 1, __ATOMIC_RELAXED, __HIP_MEMORY_SCOPE_AGENT);
        if ((unsigned)(p0 >> 32) == exp && (unsigned)(p1 >> 32) == exp) break;
      }
      f2v hv;
      hv.x = __uint_as_float((unsigned)p0);
      hv.y = __uint_as_float((unsigned)p1);
      *reinterpret_cast<f2v*>(&hl[t & 1][tid << 1]) = hv;   // one 8B ds_write
    }
    if ((tid < 128) && (t + 1 < T_STEPS))
      *reinterpret_cast<float4*>(&xl[(t + 1) & 1][tid * 4]) = xv;   // xv = x_{t+1}
    __syncthreads();   // single barrier per step

    // ======== compute region ========
    if ((tid < 128) && (t + 2 < T_STEPS))
      xv = reinterpret_cast<const float4*>(x + (size_t)(t + 2) * 512)[tid];

    float acc = xacc;
    if (t > 0) acc += dot_lds(hl[t & 1], whh);
    // reduce over 8 k-groups: xor 8,16 via ds_swizzle, xor 32 via shfl
    acc += __int_as_float(__builtin_amdgcn_ds_swizzle(__float_as_int(acc), 0x201F));
    acc += __int_as_float(__builtin_amdgcn_ds_swizzle(__float_as_int(acc), 0x401F));
    acc += __shfl_xor(acc, 32);
    acc += bias;

    // sigmoid for i,f,o; tanh (=2*sig(2x)-1) for g — exp2 + rcp fast path
    const bool isg = (gate == 2);
    float xs = isg ? 2.f * acc : acc;
    float s  = __builtin_amdgcn_rcpf(1.f + exp2f(-xs * LOG2E));
    float v  = isg ? (2.f * s - 1.f) : s;

    // gather i,f,g,o for my jloc: static swizzle, src = (lane&0x19)|(gate<<1)
    const int vb = __float_as_int(v);
    float iv = __int_as_float(__builtin_amdgcn_ds_swizzle(vb, 0x019));
    float fv = __int_as_float(__builtin_amdgcn_ds_swizzle(vb, 0x059));
    float gv = __int_as_float(__builtin_amdgcn_ds_swizzle(vb, 0x099));
    float ov = __int_as_float(__builtin_amdgcn_ds_swizzle(vb, 0x0D9));

    c = fv * c + iv * gv;
    float th = 2.f * __builtin_amdgcn_rcpf(1.f + exp2f(-LOG2E2 * c)) - 1.f;
    float hn = ov * th;

    // post tagged h_t (lanes 0,1 of every wave): fire-and-forget agent atomic
    if (lane < 2) {
      unsigned long long pk =
          ((unsigned long long)(unsigned)(t + 1) << 32) | (unsigned)__float_as_uint(hn);
      __hip_atomic_store(hbuf + ((t & 1) << 9) + wg * 8 + wid * 2 + lane, pk,
                         __ATOMIC_RELAXED, __HIP_MEMORY_SCOPE_AGENT);
    }

    // x-projection partial for t+1 (off critical path; hides post landing)
    if (t + 1 < T_STEPS) xacc = dot_lds(xl[(t + 1) & 1], wih);
  }

  // ---- softmax(h_{T-1}) by wg 0, wave 0 (precision-path expf kept) ----
  if (wg == 0 && wid == 0) {
    const unsigned long long* src = hbuf + (((T_STEPS - 1) & 1) << 9);
    float hv[8];
    {
      unsigned long long p[8];
      while (true) {
        bool ok = true;
#pragma unroll
        for (int m2 = 0; m2 < 8; ++m2) {
          p[m2] = __hip_atomic_load(src + lane * 8 + m2,
                                    __ATOMIC_RELAXED, __HIP_MEMORY_SCOPE_AGENT);
          ok &= ((unsigned)(p[m2] >> 32) == (unsigned)T_STEPS);
        }
        if (__all(ok)) break;
      }
#pragma unroll
      for (int m2 = 0; m2 < 8; ++m2) hv[m2] = __uint_as_float((unsigned)p[m2]);
    }
    float mx = hv[0];
#pragma unroll
    for (int m2 = 1; m2 < 8; ++m2) mx = fmaxf(mx, hv[m2]);
    mx = fmaxf(mx, __shfl_xor(mx, 1));
    mx = fmaxf(mx, __shfl_xor(mx, 2));
    mx = fmaxf(mx, __shfl_xor(mx, 4));
    mx = fmaxf(mx, __shfl_xor(mx, 8));
    mx = fmaxf(mx, __shfl_xor(mx, 16));
    mx = fmaxf(mx, __shfl_xor(mx, 32));
    float ex[8], sum = 0.f;
#pragma unroll
    for (int m2 = 0; m2 < 8; ++m2) { ex[m2] = expf(hv[m2] - mx); sum += ex[m2]; }
    sum += __shfl_xor(sum, 1);
    sum += __shfl_xor(sum, 2);
    sum += __shfl_xor(sum, 4);
    sum += __shfl_xor(sum, 8);
    sum += __shfl_xor(sum, 16);
    sum += __shfl_xor(sum, 32);
    float inv = 1.f / sum;
#pragma unroll
    for (int m2 = 0; m2 < 8; ++m2) out[lane * 8 + m2] = ex[m2] * inv;
  }
}

extern "C" void kernel_launch(void* const* d_in, const int* in_sizes, int n_in,
                              void* d_out, int out_size, void* d_ws, size_t ws_size,
                              hipStream_t stream) {
  const float* x   = (const float*)d_in[0];
  const float* Wih = (const float*)d_in[1];
  const float* Whh = (const float*)d_in[2];
  const float* bih = (const float*)d_in[3];
  const float* bhh = (const float*)d_in[4];
  float* out = (float*)d_out;
  unsigned long long* hbuf = (unsigned long long*)d_ws;  // 2 x 512 x 8B = 8 KB

  (void)hipMemsetAsync(d_ws, 0, 8192, stream);  // zero tags each launch (capture-safe)
  lstm_persistent<<<NWG, WGSIZE, 0, stream>>>(x, Wih, Whh, bih, bhh, out, hbuf);
}